// Round 1
// baseline (505.604 us; speedup 1.0000x reference)
//
#include <hip/hip_runtime.h>

// Problem constants (from reference setup_inputs):
//   x: (4,4096,1024) fp32 -> M=16384, dim=1024, hidden=4096, rank=16
//   w_fc: (4096,1024), w_proj: (1024,4096), u:(4096,16), v:(16,1024), fast_b:(16,16), gate scalar
// out: (16384,1024) fp32
//
// Strategy: adapter folds into W1 (x @ (u@fb@v).T), bf16 MFMA GEMMs (m97 structure).

typedef unsigned short u16;
typedef __attribute__((ext_vector_type(8))) short short8;
typedef __attribute__((ext_vector_type(4))) float float4v;

#define M_TOK   16384
#define DIM     1024
#define HID     4096

// ---------- helpers ----------

__device__ __forceinline__ u16 f2bf(float f) {
    union { float f; unsigned u; } v; v.f = f;
    unsigned r = v.u + 0x7fffu + ((v.u >> 16) & 1u);   // RNE
    return (u16)(r >> 16);
}

__device__ __forceinline__ void gload_lds16(const u16* g, u16* l) {
    __builtin_amdgcn_global_load_lds(
        (const __attribute__((address_space(1))) void*)g,
        (__attribute__((address_space(3))) void*)l, 16, 0, 0);
}

// ---------- prologue kernels ----------

// x fp32 -> bf16 (as raw u16), 4 elems/thread
__global__ __launch_bounds__(256) void cvt_x_kernel(const float* __restrict__ x,
                                                    u16* __restrict__ y) {
    int i = (blockIdx.x * 256 + threadIdx.x) * 4;
    float4 v = *reinterpret_cast<const float4*>(x + i);
    ushort4 o;
    o.x = f2bf(v.x); o.y = f2bf(v.y); o.z = f2bf(v.z); o.w = f2bf(v.w);
    *reinterpret_cast<ushort4*>(y + i) = o;
}

// T = u @ fast_b  : (4096,16)
__global__ __launch_bounds__(256) void adapter_T_kernel(const float* __restrict__ u,
                                                        const float* __restrict__ fb,
                                                        float* __restrict__ T) {
    int i = blockIdx.x * 256 + threadIdx.x;   // 65536 threads
    int row = i >> 4, r = i & 15;
    float s = 0.f;
#pragma unroll
    for (int k = 0; k < 16; k++) s += u[row * 16 + k] * fb[k * 16 + r];
    T[i] = s;
}

// W1[row][j] = bf16( tern(w_fc)*scale + gate * sum_r T[row][r]*v[r][j] ), row<4096, j<1024
__global__ __launch_bounds__(256) void build_w1_kernel(const float* __restrict__ w,
                                                       const float* __restrict__ T,
                                                       const float* __restrict__ v,
                                                       const float* __restrict__ gate,
                                                       u16* __restrict__ W1) {
    const int row = blockIdx.x, tid = threadIdx.x;
    float s = 0.f;
#pragma unroll
    for (int jj = 0; jj < 4; jj++) s += fabsf(w[row * 1024 + tid + jj * 256]);
#pragma unroll
    for (int o = 32; o > 0; o >>= 1) s += __shfl_down(s, o, 64);
    __shared__ float red[4];
    if ((tid & 63) == 0) red[tid >> 6] = s;
    __syncthreads();
    const float scale = fmaxf((red[0] + red[1] + red[2] + red[3]) * (1.f / 1024.f), 1e-5f);
    const float g = gate[0];
    float t[16];
#pragma unroll
    for (int r = 0; r < 16; r++) t[r] = T[row * 16 + r];
#pragma unroll
    for (int jj = 0; jj < 4; jj++) {
        const int j = tid + jj * 256;
        const float wv = w[row * 1024 + j];
        float tern = rintf(wv / scale);
        tern = fminf(1.f, fmaxf(-1.f, tern));
        float ad = 0.f;
#pragma unroll
        for (int r = 0; r < 16; r++) ad += t[r] * v[r * 1024 + j];
        W1[row * 1024 + j] = f2bf(tern * scale + g * ad);
    }
}

// W2[row][j] = bf16( tern(w_proj)*scale ), row<1024, j<4096
__global__ __launch_bounds__(256) void build_w2_kernel(const float* __restrict__ w,
                                                       u16* __restrict__ W2) {
    const int row = blockIdx.x, tid = threadIdx.x;
    float s = 0.f;
#pragma unroll
    for (int jj = 0; jj < 16; jj++) s += fabsf(w[row * 4096 + tid + jj * 256]);
#pragma unroll
    for (int o = 32; o > 0; o >>= 1) s += __shfl_down(s, o, 64);
    __shared__ float red[4];
    if ((tid & 63) == 0) red[tid >> 6] = s;
    __syncthreads();
    const float scale = fmaxf((red[0] + red[1] + red[2] + red[3]) * (1.f / 4096.f), 1e-5f);
#pragma unroll
    for (int jj = 0; jj < 16; jj++) {
        const int j = tid + jj * 256;
        float tern = rintf(w[row * 4096 + j] / scale);
        tern = fminf(1.f, fmaxf(-1.f, tern));
        W2[row * 4096 + j] = f2bf(tern * scale);
    }
}

// ---------- GEMM: C[M,N] = A[M,K] @ B[N,K]^T (both bf16 row-major) ----------
// m97 structure: 128x128 tile, BK=32, 4 waves -> 64x64 each via 4x4 mfma 16x16x32.
// EPI 0: relu(v)^2 -> bf16 store.  EPI 1: fp32 store.
template <int N, int K, int EPI>
__global__ __launch_bounds__(256, 2) void gemm_bt(const u16* __restrict__ A,
                                                  const u16* __restrict__ B,
                                                  void* __restrict__ Cv) {
    __shared__ alignas(16) u16 As[128 * 32];
    __shared__ alignas(16) u16 Bs[128 * 32];
    const int tid = threadIdx.x;
    const int bn = blockIdx.x, bm = blockIdx.y;
    const int wave = tid >> 6, lane = tid & 63;
    const int wm = (wave >> 1) << 6;   // 0 or 64 (row half)
    const int wn = (wave & 1) << 6;    // 0 or 64 (col half)
    const int lr = lane & 15, quad = lane >> 4;

    float4v acc[4][4];
#pragma unroll
    for (int i = 0; i < 4; i++)
#pragma unroll
        for (int j = 0; j < 4; j++) acc[i][j] = (float4v)0.0f;

    // staging map: 16B chunk c -> row=c>>2, kq=c&3 ; LDS offset = c*16B (lane-contiguous)
    const int c0 = tid, c1 = tid + 256;
    const u16* Ag0 = A + (size_t)(bm * 128 + (c0 >> 2)) * K + (c0 & 3) * 8;
    const u16* Ag1 = A + (size_t)(bm * 128 + (c1 >> 2)) * K + (c1 & 3) * 8;
    const u16* Bg0 = B + (size_t)(bn * 128 + (c0 >> 2)) * K + (c0 & 3) * 8;
    const u16* Bg1 = B + (size_t)(bn * 128 + (c1 >> 2)) * K + (c1 & 3) * 8;
    u16* Al0 = As + c0 * 8;
    u16* Al1 = As + c1 * 8;
    u16* Bl0 = Bs + c0 * 8;
    u16* Bl1 = Bs + c1 * 8;

    // fragment read bases: A[m=lane&15][k=quad*8+j] (guide §3, m89-verified)
    const u16* pa = &As[(wm + lr) * 32 + quad * 8];
    const u16* pb = &Bs[(wn + lr) * 32 + quad * 8];

    for (int k0 = 0; k0 < K; k0 += 32) {
        gload_lds16(Ag0 + k0, Al0);
        gload_lds16(Ag1 + k0, Al1);
        gload_lds16(Bg0 + k0, Bl0);
        gload_lds16(Bg1 + k0, Bl1);
        __syncthreads();
        short8 af[4], bf[4];
#pragma unroll
        for (int i = 0; i < 4; i++)
            af[i] = *reinterpret_cast<const short8*>(pa + i * 16 * 32);
#pragma unroll
        for (int j = 0; j < 4; j++)
            bf[j] = *reinterpret_cast<const short8*>(pb + j * 16 * 32);
#pragma unroll
        for (int i = 0; i < 4; i++)
#pragma unroll
            for (int j = 0; j < 4; j++)
                acc[i][j] = __builtin_amdgcn_mfma_f32_16x16x32_bf16(af[i], bf[j], acc[i][j],
                                                                    0, 0, 0);
        __syncthreads();
    }

    // C/D layout: col=lane&15, row=quad*4+reg (m89/m91-verified)
    const int row0 = bm * 128 + wm + quad * 4;
    const int col0 = bn * 128 + wn + lr;
#pragma unroll
    for (int i = 0; i < 4; i++)
#pragma unroll
        for (int j = 0; j < 4; j++) {
            const int col = col0 + j * 16;
#pragma unroll
            for (int r = 0; r < 4; r++) {
                const int row = row0 + i * 16 + r;
                const float vv = acc[i][j][r];
                if (EPI == 0) {
                    const float rr = fmaxf(vv, 0.f);
                    ((u16*)Cv)[(size_t)row * N + col] = f2bf(rr * rr);
                } else {
                    ((float*)Cv)[(size_t)row * N + col] = vv;
                }
            }
        }
}

// ---------- launch ----------

extern "C" void kernel_launch(void* const* d_in, const int* in_sizes, int n_in,
                              void* d_out, int out_size, void* d_ws, size_t ws_size,
                              hipStream_t stream) {
    const float* x      = (const float*)d_in[0];
    const float* fast_b = (const float*)d_in[1];
    const float* w_fc   = (const float*)d_in[2];
    const float* w_proj = (const float*)d_in[3];
    const float* u      = (const float*)d_in[4];
    const float* v      = (const float*)d_in[5];
    const float* gate   = (const float*)d_in[6];
    float* out = (float*)d_out;

    char* ws = (char*)d_ws;
    u16*   Xb  = (u16*)(ws + 0);                         // 16384*1024*2 = 32 MB
    u16*   W1  = (u16*)(ws + 33554432);                  // 4096*1024*2  =  8 MB
    u16*   W2  = (u16*)(ws + 41943040);                  // 1024*4096*2  =  8 MB
    u16*   RSQ = (u16*)(ws + 50331648);                  // 16384*4096*2 = 128 MB
    float* T   = (float*)(ws + 184549376);               // 4096*16*4    = 256 KB

    cvt_x_kernel<<<M_TOK * DIM / (256 * 4), 256, 0, stream>>>(x, Xb);
    adapter_T_kernel<<<HID * 16 / 256, 256, 0, stream>>>(u, fast_b, T);
    build_w1_kernel<<<HID, 256, 0, stream>>>(w_fc, T, v, gate, W1);
    build_w2_kernel<<<DIM, 256, 0, stream>>>(w_proj, W2);

    // GEMM1: (16384,1024) @ (4096,1024)^T -> relu^2 bf16 (16384,4096)
    gemm_bt<HID, DIM, 0><<<dim3(HID / 128, M_TOK / 128), 256, 0, stream>>>(Xb, W1, RSQ);
    // GEMM2: (16384,4096) @ (1024,4096)^T -> fp32 out (16384,1024)
    gemm_bt<DIM, HID, 1><<<dim3(DIM / 128, M_TOK / 128), 256, 0, stream>>>(RSQ, W2, out);
}

// Round 2
// 503.200 us; speedup vs baseline: 1.0048x; 1.0048x over previous
//
#include <hip/hip_runtime.h>

// Problem constants (from reference setup_inputs):
//   x: (4,4096,1024) fp32 -> M=16384, dim=1024, hidden=4096, rank=16
//   w_fc: (4096,1024), w_proj: (1024,4096), u:(4096,16), v:(16,1024), fast_b:(16,16), gate scalar
// out: (16384,1024) fp32
//
// Strategy: adapter folds into W1 (x @ (u@fb@v).T), bf16 MFMA GEMMs (m97 structure).
// R1: XOR-swizzled LDS K-quad placement to kill ds_read_b128 bank conflicts
//     (R0 measured 1.68e7 conflict cycles/dispatch ~= 14% of GEMM time).

typedef unsigned short u16;
typedef __attribute__((ext_vector_type(8))) short short8;
typedef __attribute__((ext_vector_type(4))) float float4v;

#define M_TOK   16384
#define DIM     1024
#define HID     4096

// ---------- helpers ----------

__device__ __forceinline__ u16 f2bf(float f) {
    union { float f; unsigned u; } v; v.f = f;
    unsigned r = v.u + 0x7fffu + ((v.u >> 16) & 1u);   // RNE
    return (u16)(r >> 16);
}

__device__ __forceinline__ void gload_lds16(const u16* g, u16* l) {
    __builtin_amdgcn_global_load_lds(
        (const __attribute__((address_space(1))) void*)g,
        (__attribute__((address_space(3))) void*)l, 16, 0, 0);
}

// ---------- prologue kernels ----------

// x fp32 -> bf16 (as raw u16), 4 elems/thread
__global__ __launch_bounds__(256) void cvt_x_kernel(const float* __restrict__ x,
                                                    u16* __restrict__ y) {
    int i = (blockIdx.x * 256 + threadIdx.x) * 4;
    float4 v = *reinterpret_cast<const float4*>(x + i);
    ushort4 o;
    o.x = f2bf(v.x); o.y = f2bf(v.y); o.z = f2bf(v.z); o.w = f2bf(v.w);
    *reinterpret_cast<ushort4*>(y + i) = o;
}

// T = u @ fast_b  : (4096,16)
__global__ __launch_bounds__(256) void adapter_T_kernel(const float* __restrict__ u,
                                                        const float* __restrict__ fb,
                                                        float* __restrict__ T) {
    int i = blockIdx.x * 256 + threadIdx.x;   // 65536 threads
    int row = i >> 4, r = i & 15;
    float s = 0.f;
#pragma unroll
    for (int k = 0; k < 16; k++) s += u[row * 16 + k] * fb[k * 16 + r];
    T[i] = s;
}

// W1[row][j] = bf16( tern(w_fc)*scale + gate * sum_r T[row][r]*v[r][j] ), row<4096, j<1024
__global__ __launch_bounds__(256) void build_w1_kernel(const float* __restrict__ w,
                                                       const float* __restrict__ T,
                                                       const float* __restrict__ v,
                                                       const float* __restrict__ gate,
                                                       u16* __restrict__ W1) {
    const int row = blockIdx.x, tid = threadIdx.x;
    float s = 0.f;
#pragma unroll
    for (int jj = 0; jj < 4; jj++) s += fabsf(w[row * 1024 + tid + jj * 256]);
#pragma unroll
    for (int o = 32; o > 0; o >>= 1) s += __shfl_down(s, o, 64);
    __shared__ float red[4];
    if ((tid & 63) == 0) red[tid >> 6] = s;
    __syncthreads();
    const float scale = fmaxf((red[0] + red[1] + red[2] + red[3]) * (1.f / 1024.f), 1e-5f);
    const float g = gate[0];
    float t[16];
#pragma unroll
    for (int r = 0; r < 16; r++) t[r] = T[row * 16 + r];
#pragma unroll
    for (int jj = 0; jj < 4; jj++) {
        const int j = tid + jj * 256;
        const float wv = w[row * 1024 + j];
        float tern = rintf(wv / scale);
        tern = fminf(1.f, fmaxf(-1.f, tern));
        float ad = 0.f;
#pragma unroll
        for (int r = 0; r < 16; r++) ad += t[r] * v[r * 1024 + j];
        W1[row * 1024 + j] = f2bf(tern * scale + g * ad);
    }
}

// W2[row][j] = bf16( tern(w_proj)*scale ), row<1024, j<4096
__global__ __launch_bounds__(256) void build_w2_kernel(const float* __restrict__ w,
                                                       u16* __restrict__ W2) {
    const int row = blockIdx.x, tid = threadIdx.x;
    float s = 0.f;
#pragma unroll
    for (int jj = 0; jj < 16; jj++) s += fabsf(w[row * 4096 + tid + jj * 256]);
#pragma unroll
    for (int o = 32; o > 0; o >>= 1) s += __shfl_down(s, o, 64);
    __shared__ float red[4];
    if ((tid & 63) == 0) red[tid >> 6] = s;
    __syncthreads();
    const float scale = fmaxf((red[0] + red[1] + red[2] + red[3]) * (1.f / 4096.f), 1e-5f);
#pragma unroll
    for (int jj = 0; jj < 16; jj++) {
        const int j = tid + jj * 256;
        float tern = rintf(w[row * 4096 + j] / scale);
        tern = fminf(1.f, fmaxf(-1.f, tern));
        W2[row * 4096 + j] = f2bf(tern * scale);
    }
}

// ---------- GEMM: C[M,N] = A[M,K] @ B[N,K]^T (both bf16 row-major) ----------
// m97 structure: 128x128 tile, BK=32, 4 waves -> 64x64 each via 4x4 mfma 16x16x32.
// LDS layout per row: 4 x 16B positions; position p of row r holds k-quad p ^ ((r>>1)&3).
// This spreads consecutive-lane ds_read_b128 bank-group bases over all 32 banks.
// EPI 0: relu(v)^2 -> bf16 store.  EPI 1: fp32 store.
template <int N, int K, int EPI>
__global__ __launch_bounds__(256, 2) void gemm_bt(const u16* __restrict__ A,
                                                  const u16* __restrict__ B,
                                                  void* __restrict__ Cv) {
    __shared__ alignas(16) u16 As[128 * 32];
    __shared__ alignas(16) u16 Bs[128 * 32];
    const int tid = threadIdx.x;
    const int bn = blockIdx.x, bm = blockIdx.y;
    const int wave = tid >> 6, lane = tid & 63;
    const int wm = (wave >> 1) << 6;   // 0 or 64 (row half)
    const int wn = (wave & 1) << 6;    // 0 or 64 (col half)
    const int lr = lane & 15, quad = lane >> 4;

    float4v acc[4][4];
#pragma unroll
    for (int i = 0; i < 4; i++)
#pragma unroll
        for (int j = 0; j < 4; j++) acc[i][j] = (float4v)0.0f;

    // staging map: 16B chunk c -> row=c>>2, pos=c&3; that position stores
    // k-quad kq = pos ^ ((row>>1)&3). LDS dest stays c*16B (lane-contiguous).
    const int c0 = tid, c1 = tid + 256;
    const int r0s = c0 >> 2, r1s = c1 >> 2;
    const int kq0 = (c0 & 3) ^ ((r0s >> 1) & 3);
    const int kq1 = (c1 & 3) ^ ((r1s >> 1) & 3);
    const u16* Ag0 = A + (size_t)(bm * 128 + r0s) * K + kq0 * 8;
    const u16* Ag1 = A + (size_t)(bm * 128 + r1s) * K + kq1 * 8;
    const u16* Bg0 = B + (size_t)(bn * 128 + r0s) * K + kq0 * 8;
    const u16* Bg1 = B + (size_t)(bn * 128 + r1s) * K + kq1 * 8;
    u16* Al0 = As + c0 * 8;
    u16* Al1 = As + c1 * 8;
    u16* Bl0 = Bs + c0 * 8;
    u16* Bl1 = Bs + c1 * 8;

    // fragment read bases: lane needs row (wm|wn)+lr+i*16, k-quad `quad`, which
    // lives at position quad ^ ((lr>>1)&3)  (wm / i*16 don't touch bits [1:2]).
    const int pos = quad ^ ((lr >> 1) & 3);
    const u16* pa = &As[(wm + lr) * 32 + pos * 8];
    const u16* pb = &Bs[(wn + lr) * 32 + pos * 8];

    for (int k0 = 0; k0 < K; k0 += 32) {
        gload_lds16(Ag0 + k0, Al0);
        gload_lds16(Ag1 + k0, Al1);
        gload_lds16(Bg0 + k0, Bl0);
        gload_lds16(Bg1 + k0, Bl1);
        __syncthreads();
        short8 af[4], bf[4];
#pragma unroll
        for (int i = 0; i < 4; i++)
            af[i] = *reinterpret_cast<const short8*>(pa + i * 16 * 32);
#pragma unroll
        for (int j = 0; j < 4; j++)
            bf[j] = *reinterpret_cast<const short8*>(pb + j * 16 * 32);
#pragma unroll
        for (int i = 0; i < 4; i++)
#pragma unroll
            for (int j = 0; j < 4; j++)
                acc[i][j] = __builtin_amdgcn_mfma_f32_16x16x32_bf16(af[i], bf[j], acc[i][j],
                                                                    0, 0, 0);
        __syncthreads();
    }

    // C/D layout: col=lane&15, row=quad*4+reg (m89/m91-verified)
    const int row0 = bm * 128 + wm + quad * 4;
    const int col0 = bn * 128 + wn + lr;
#pragma unroll
    for (int i = 0; i < 4; i++)
#pragma unroll
        for (int j = 0; j < 4; j++) {
            const int col = col0 + j * 16;
#pragma unroll
            for (int r = 0; r < 4; r++) {
                const int row = row0 + i * 16 + r;
                const float vv = acc[i][j][r];
                if (EPI == 0) {
                    const float rr = fmaxf(vv, 0.f);
                    ((u16*)Cv)[(size_t)row * N + col] = f2bf(rr * rr);
                } else {
                    ((float*)Cv)[(size_t)row * N + col] = vv;
                }
            }
        }
}

// ---------- launch ----------

extern "C" void kernel_launch(void* const* d_in, const int* in_sizes, int n_in,
                              void* d_out, int out_size, void* d_ws, size_t ws_size,
                              hipStream_t stream) {
    const float* x      = (const float*)d_in[0];
    const float* fast_b = (const float*)d_in[1];
    const float* w_fc   = (const float*)d_in[2];
    const float* w_proj = (const float*)d_in[3];
    const float* u      = (const float*)d_in[4];
    const float* v      = (const float*)d_in[5];
    const float* gate   = (const float*)d_in[6];
    float* out = (float*)d_out;

    char* ws = (char*)d_ws;
    u16*   Xb  = (u16*)(ws + 0);                         // 16384*1024*2 = 32 MB
    u16*   W1  = (u16*)(ws + 33554432);                  // 4096*1024*2  =  8 MB
    u16*   W2  = (u16*)(ws + 41943040);                  // 1024*4096*2  =  8 MB
    u16*   RSQ = (u16*)(ws + 50331648);                  // 16384*4096*2 = 128 MB
    float* T   = (float*)(ws + 184549376);               // 4096*16*4    = 256 KB

    cvt_x_kernel<<<M_TOK * DIM / (256 * 4), 256, 0, stream>>>(x, Xb);
    adapter_T_kernel<<<HID * 16 / 256, 256, 0, stream>>>(u, fast_b, T);
    build_w1_kernel<<<HID, 256, 0, stream>>>(w_fc, T, v, gate, W1);
    build_w2_kernel<<<DIM, 256, 0, stream>>>(w_proj, W2);

    // GEMM1: (16384,1024) @ (4096,1024)^T -> relu^2 bf16 (16384,4096)
    gemm_bt<HID, DIM, 0><<<dim3(HID / 128, M_TOK / 128), 256, 0, stream>>>(Xb, W1, RSQ);
    // GEMM2: (16384,4096) @ (1024,4096)^T -> fp32 out (16384,1024)
    gemm_bt<DIM, HID, 1><<<dim3(DIM / 128, M_TOK / 128), 256, 0, stream>>>(RSQ, W2, out);
}

// Round 3
// 488.197 us; speedup vs baseline: 1.0357x; 1.0307x over previous
//
#include <hip/hip_runtime.h>

// Problem constants (from reference setup_inputs):
//   x: (4,4096,1024) fp32 -> M=16384, dim=1024, hidden=4096, rank=16
//   w_fc: (4096,1024), w_proj: (1024,4096), u:(4096,16), v:(16,1024), fast_b:(16,16), gate scalar
// out: (16384,1024) fp32
//
// Strategy: adapter folds into W1 (x @ (u@fb@v).T), bf16 MFMA GEMMs.
// R1: XOR-swizzled LDS K-quad placement -> SQ_LDS_BANK_CONFLICT 1.68e7 -> 0 (neutral on time).
// R2: double-buffered prefetch K-loop with raw s_barrier + explicit s_waitcnt vmcnt(4)
//     so next tile's global_load_lds stay in flight across the barrier
//     (R1 showed ~70% of each iter is exposed staging latency; __syncthreads drains vmcnt(0)).

typedef unsigned short u16;
typedef __attribute__((ext_vector_type(8))) short short8;
typedef __attribute__((ext_vector_type(4))) float float4v;

#define M_TOK   16384
#define DIM     1024
#define HID     4096

// ---------- helpers ----------

__device__ __forceinline__ u16 f2bf(float f) {
    union { float f; unsigned u; } v; v.f = f;
    unsigned r = v.u + 0x7fffu + ((v.u >> 16) & 1u);   // RNE
    return (u16)(r >> 16);
}

__device__ __forceinline__ void gload_lds16(const u16* g, u16* l) {
    __builtin_amdgcn_global_load_lds(
        (const __attribute__((address_space(1))) void*)g,
        (__attribute__((address_space(3))) void*)l, 16, 0, 0);
}

// ---------- prologue kernels ----------

__global__ __launch_bounds__(256) void cvt_x_kernel(const float* __restrict__ x,
                                                    u16* __restrict__ y) {
    int i = (blockIdx.x * 256 + threadIdx.x) * 4;
    float4 v = *reinterpret_cast<const float4*>(x + i);
    ushort4 o;
    o.x = f2bf(v.x); o.y = f2bf(v.y); o.z = f2bf(v.z); o.w = f2bf(v.w);
    *reinterpret_cast<ushort4*>(y + i) = o;
}

__global__ __launch_bounds__(256) void adapter_T_kernel(const float* __restrict__ u,
                                                        const float* __restrict__ fb,
                                                        float* __restrict__ T) {
    int i = blockIdx.x * 256 + threadIdx.x;
    int row = i >> 4, r = i & 15;
    float s = 0.f;
#pragma unroll
    for (int k = 0; k < 16; k++) s += u[row * 16 + k] * fb[k * 16 + r];
    T[i] = s;
}

__global__ __launch_bounds__(256) void build_w1_kernel(const float* __restrict__ w,
                                                       const float* __restrict__ T,
                                                       const float* __restrict__ v,
                                                       const float* __restrict__ gate,
                                                       u16* __restrict__ W1) {
    const int row = blockIdx.x, tid = threadIdx.x;
    float s = 0.f;
#pragma unroll
    for (int jj = 0; jj < 4; jj++) s += fabsf(w[row * 1024 + tid + jj * 256]);
#pragma unroll
    for (int o = 32; o > 0; o >>= 1) s += __shfl_down(s, o, 64);
    __shared__ float red[4];
    if ((tid & 63) == 0) red[tid >> 6] = s;
    __syncthreads();
    const float scale = fmaxf((red[0] + red[1] + red[2] + red[3]) * (1.f / 1024.f), 1e-5f);
    const float g = gate[0];
    float t[16];
#pragma unroll
    for (int r = 0; r < 16; r++) t[r] = T[row * 16 + r];
#pragma unroll
    for (int jj = 0; jj < 4; jj++) {
        const int j = tid + jj * 256;
        const float wv = w[row * 1024 + j];
        float tern = rintf(wv / scale);
        tern = fminf(1.f, fmaxf(-1.f, tern));
        float ad = 0.f;
#pragma unroll
        for (int r = 0; r < 16; r++) ad += t[r] * v[r * 1024 + j];
        W1[row * 1024 + j] = f2bf(tern * scale + g * ad);
    }
}

__global__ __launch_bounds__(256) void build_w2_kernel(const float* __restrict__ w,
                                                       u16* __restrict__ W2) {
    const int row = blockIdx.x, tid = threadIdx.x;
    float s = 0.f;
#pragma unroll
    for (int jj = 0; jj < 16; jj++) s += fabsf(w[row * 4096 + tid + jj * 256]);
#pragma unroll
    for (int o = 32; o > 0; o >>= 1) s += __shfl_down(s, o, 64);
    __shared__ float red[4];
    if ((tid & 63) == 0) red[tid >> 6] = s;
    __syncthreads();
    const float scale = fmaxf((red[0] + red[1] + red[2] + red[3]) * (1.f / 4096.f), 1e-5f);
#pragma unroll
    for (int jj = 0; jj < 16; jj++) {
        const int j = tid + jj * 256;
        float tern = rintf(w[row * 4096 + j] / scale);
        tern = fminf(1.f, fmaxf(-1.f, tern));
        W2[row * 4096 + j] = f2bf(tern * scale);
    }
}

// ---------- GEMM: C[M,N] = A[M,K] @ B[N,K]^T (both bf16 row-major) ----------
// 128x128 tile, BK=32, 4 waves -> 64x64 each via 4x4 mfma 16x16x32.
// LDS: double-buffered, XOR-swizzled K-quad placement (conflict-free).
// K-loop: prefetch next tile -> s_waitcnt vmcnt(4) -> raw s_barrier -> compute
//         -> raw s_barrier -> swap. Loads stay in flight across barriers.
// EPI 0: relu(v)^2 -> bf16 store.  EPI 1: fp32 store.
template <int N, int K, int EPI>
__global__ __launch_bounds__(256, 2) void gemm_bt(const u16* __restrict__ A,
                                                  const u16* __restrict__ B,
                                                  void* __restrict__ Cv) {
    __shared__ alignas(16) u16 As[2][128 * 32];
    __shared__ alignas(16) u16 Bs[2][128 * 32];
    const int tid = threadIdx.x;
    const int bn = blockIdx.x, bm = blockIdx.y;
    const int wave = tid >> 6, lane = tid & 63;
    const int wm = (wave >> 1) << 6;
    const int wn = (wave & 1) << 6;
    const int lr = lane & 15, quad = lane >> 4;

    float4v acc[4][4];
#pragma unroll
    for (int i = 0; i < 4; i++)
#pragma unroll
        for (int j = 0; j < 4; j++) acc[i][j] = (float4v)0.0f;

    // staging map: 16B chunk c -> row=c>>2, pos=c&3; position p of row r holds
    // k-quad p ^ ((r>>1)&3). LDS dest stays c*16B (lane-contiguous, required).
    const int c0 = tid, c1 = tid + 256;
    const int r0s = c0 >> 2, r1s = c1 >> 2;
    const int kq0 = (c0 & 3) ^ ((r0s >> 1) & 3);
    const int kq1 = (c1 & 3) ^ ((r1s >> 1) & 3);
    const u16* Ag0 = A + (size_t)(bm * 128 + r0s) * K + kq0 * 8;
    const u16* Ag1 = A + (size_t)(bm * 128 + r1s) * K + kq1 * 8;
    const u16* Bg0 = B + (size_t)(bn * 128 + r0s) * K + kq0 * 8;
    const u16* Bg1 = B + (size_t)(bn * 128 + r1s) * K + kq1 * 8;

    // fragment read offsets (within a buffer)
    const int pos = quad ^ ((lr >> 1) & 3);
    const int offA = (wm + lr) * 32 + pos * 8;
    const int offB = (wn + lr) * 32 + pos * 8;

#define ISSUE(buf_, k0_)                                   \
    do {                                                   \
        gload_lds16(Ag0 + (k0_), &As[buf_][c0 * 8]);       \
        gload_lds16(Ag1 + (k0_), &As[buf_][c1 * 8]);       \
        gload_lds16(Bg0 + (k0_), &Bs[buf_][c0 * 8]);       \
        gload_lds16(Bg1 + (k0_), &Bs[buf_][c1 * 8]);       \
    } while (0)

#define COMPUTE(buf_)                                                          \
    do {                                                                       \
        const u16* pa_ = &As[buf_][offA];                                      \
        const u16* pb_ = &Bs[buf_][offB];                                      \
        short8 af[4], bfr[4];                                                  \
        _Pragma("unroll") for (int i = 0; i < 4; i++)                          \
            af[i] = *reinterpret_cast<const short8*>(pa_ + i * 16 * 32);       \
        _Pragma("unroll") for (int j = 0; j < 4; j++)                          \
            bfr[j] = *reinterpret_cast<const short8*>(pb_ + j * 16 * 32);      \
        _Pragma("unroll") for (int i = 0; i < 4; i++)                          \
            _Pragma("unroll") for (int j = 0; j < 4; j++)                      \
                acc[i][j] = __builtin_amdgcn_mfma_f32_16x16x32_bf16(           \
                    af[i], bfr[j], acc[i][j], 0, 0, 0);                        \
    } while (0)

    constexpr int NIT = K / 32;
    ISSUE(0, 0);
    int buf = 0;
#pragma unroll 2
    for (int it = 0; it < NIT - 1; ++it) {
        ISSUE(buf ^ 1, (it + 1) * 32);
        asm volatile("s_waitcnt vmcnt(4)" ::: "memory");
        __builtin_amdgcn_s_barrier();
        asm volatile("" ::: "memory");
        COMPUTE(buf);
        asm volatile("" ::: "memory");
        __builtin_amdgcn_s_barrier();
        asm volatile("" ::: "memory");
        buf ^= 1;
    }
    asm volatile("s_waitcnt vmcnt(0)" ::: "memory");
    __builtin_amdgcn_s_barrier();
    asm volatile("" ::: "memory");
    COMPUTE(buf);

#undef ISSUE
#undef COMPUTE

    // C/D layout: col=lane&15, row=quad*4+reg (m89/m91-verified)
    const int row0 = bm * 128 + wm + quad * 4;
    const int col0 = bn * 128 + wn + lr;
#pragma unroll
    for (int i = 0; i < 4; i++)
#pragma unroll
        for (int j = 0; j < 4; j++) {
            const int col = col0 + j * 16;
#pragma unroll
            for (int r = 0; r < 4; r++) {
                const int row = row0 + i * 16 + r;
                const float vv = acc[i][j][r];
                if (EPI == 0) {
                    const float rr = fmaxf(vv, 0.f);
                    ((u16*)Cv)[(size_t)row * N + col] = f2bf(rr * rr);
                } else {
                    ((float*)Cv)[(size_t)row * N + col] = vv;
                }
            }
        }
}

// ---------- launch ----------

extern "C" void kernel_launch(void* const* d_in, const int* in_sizes, int n_in,
                              void* d_out, int out_size, void* d_ws, size_t ws_size,
                              hipStream_t stream) {
    const float* x      = (const float*)d_in[0];
    const float* fast_b = (const float*)d_in[1];
    const float* w_fc   = (const float*)d_in[2];
    const float* w_proj = (const float*)d_in[3];
    const float* u      = (const float*)d_in[4];
    const float* v      = (const float*)d_in[5];
    const float* gate   = (const float*)d_in[6];
    float* out = (float*)d_out;

    char* ws = (char*)d_ws;
    u16*   Xb  = (u16*)(ws + 0);                         // 16384*1024*2 = 32 MB
    u16*   W1  = (u16*)(ws + 33554432);                  // 4096*1024*2  =  8 MB
    u16*   W2  = (u16*)(ws + 41943040);                  // 1024*4096*2  =  8 MB
    u16*   RSQ = (u16*)(ws + 50331648);                  // 16384*4096*2 = 128 MB
    float* T   = (float*)(ws + 184549376);               // 4096*16*4    = 256 KB

    cvt_x_kernel<<<M_TOK * DIM / (256 * 4), 256, 0, stream>>>(x, Xb);
    adapter_T_kernel<<<HID * 16 / 256, 256, 0, stream>>>(u, fast_b, T);
    build_w1_kernel<<<HID, 256, 0, stream>>>(w_fc, T, v, gate, W1);
    build_w2_kernel<<<DIM, 256, 0, stream>>>(w_proj, W2);

    // GEMM1: (16384,1024) @ (4096,1024)^T -> relu^2 bf16 (16384,4096)
    gemm_bt<HID, DIM, 0><<<dim3(HID / 128, M_TOK / 128), 256, 0, stream>>>(Xb, W1, RSQ);
    // GEMM2: (16384,4096) @ (1024,4096)^T -> fp32 out (16384,1024)
    gemm_bt<DIM, HID, 1><<<dim3(DIM / 128, M_TOK / 128), 256, 0, stream>>>(RSQ, W2, out);
}